// Round 7
// baseline (126.620 us; speedup 1.0000x reference)
//
#include <hip/hip_runtime.h>

#define MDIM 512
#define LCH  31
#define CDIM 542   // MD + L - 1
#define INW  1024
#define NELEM (MDIM*MDIM*LCH)   // 8126464
#define GB3  2048               // k3/k4 grid blocks

// ---- k1 pipelined geometry ----
#define TNK  32                 // output n-cols per k1 block
#define MPER 16                 // m rows per k1 block
#define SEG  2048               // floats per LDS row slot (covers 66 cols * 31 + pad)
#define RSK  (INW*LCH)          // floats per input row = 31744

// ws layout (floats): Xm[m][l][n], yn[m][c], pmaxY[512], pmaxT[2048], scl[2]
#define XM_OFF  0
#define YN_OFF  (MDIM*LCH*MDIM)
#define PMY_OFF (YN_OFF + MDIM*CDIM)
#define PMT_OFF (PMY_OFF + MDIM)
#define SCL_OFF (PMT_OFF + GB3)

typedef const __attribute__((address_space(1))) void* gas_ptr;
typedef __attribute__((address_space(3))) void* las_ptr;

// Direct global->LDS copy, 16 B per lane. LDS dest is wave-uniform base
// (+lane*16 by HW); global src is per-lane (clamped addresses allowed).
__device__ __forceinline__ void gload16(const float* g, float* l) {
    __builtin_amdgcn_global_load_lds((gas_ptr)g, (las_ptr)l, 16, 0, 0);
}

// K1: fused bilinear-resize + l-conv + H-mult, software-pipelined.
// Block = (mgroup of 16 rows) x (ntile of 32 cols). Rotating 8-slot LDS
// window of raw X row segments: each row segment loaded ONCE per stripe
// (vertical reuse in LDS). Stage for m+1 issued before computing m; raw
// s_barrier + manual waitcnt keep the prefetch in flight across barriers.
// All OOB (clamped) values are consumed only with zero weights:
//   row -1 / 1024  -> wy0/wy3 = 0 at m = 0/511
//   col -1 / 1024  -> wx0/wx3 = 0 at n = 0/511
__global__ __launch_bounds__(256) void k1_fused(const float* __restrict__ X,
                                                const float* __restrict__ H,
                                                float* __restrict__ Xm) {
    __shared__ float rows[8][SEG];   // 64 KB raw row segments, slot = row & 7
    __shared__ float xv[SEG];        // 8 KB vertically-combined tile
    __shared__ float hb[2][1024];    // 8 KB H tile, double-buffered by m&1

    const int bid   = blockIdx.x;
    const int ntile = bid & 15;          // consecutive bids -> XCD round-robin:
    const int m0    = (bid >> 4) * MPER; // each n-stripe pinned to one XCD
    const int n0    = ntile * TNK;
    const int tid   = threadIdx.x;
    const int wave  = tid >> 6;
    const int lane  = tid & 63;
    const int qa    = (2*n0 - 1)*LCH - 1;   // float4-aligned tile start (q offset)

    auto rowbase = [&](int r) {
        return X + (size_t)min(max(r, 0), INW-1) * RSK;
    };
    auto stage_row_chunk = [&](int r, int chunk) {     // chunk in [0,8)
        int q = qa + 256*chunk + 4*lane;
        q = min(max(q, 0), RSK - 4);                   // clamp -> zero-weight taps
        gload16(rowbase(r) + q, &rows[r & 7][256*chunk]);
    };
    auto stage_h_chunk = [&](int m, int chunk) {       // chunk in [0,4)
        long g = ((long)m*MDIM + n0)*LCH + 256*chunk + 4*lane;
        g = min(g, (long)(NELEM - 4));                 // tail overread clamp (unread)
        gload16(H + g, &hb[m & 1][256*chunk]);
    };

    // prologue: rows 2m0-1..2m0+2 + H[m0]
    for (int c = wave; c < 36; c += 4) {
        if (c < 32) stage_row_chunk(2*m0 - 1 + (c >> 3), c & 7);
        else        stage_h_chunk(m0, c & 3);
    }
    asm volatile("s_waitcnt vmcnt(0)" ::: "memory");
    __builtin_amdgcn_sched_barrier(0);
    __builtin_amdgcn_s_barrier();

    for (int k = 0; k < MPER; ++k) {
        const int m = m0 + k;

        // stage rows + H for m+1 (stays in flight until end-of-iter wait)
        if (k + 1 < MPER) {
            for (int c = wave; c < 20; c += 4) {
                if (c < 16) stage_row_chunk(2*m + 3 + (c >> 3), c & 7);
                else        stage_h_chunk(m + 1, c & 3);
            }
        }

        // vertical 4-tap combine: rows -> xv (float4 in LDS)
        float wy0=0.125f, wy1=0.375f, wy2=0.375f, wy3=0.125f;
        if (m == 0)        wy0 = 0.f;
        if (m == MDIM-1)   wy3 = 0.f;
        if (m == 0 || m == MDIM-1) {
            const float inv = 1.0f/0.875f;
            wy0*=inv; wy1*=inv; wy2*=inv; wy3*=inv;
        }
        {
            const float4* r0 = (const float4*)rows[(2*m - 1) & 7];
            const float4* r1 = (const float4*)rows[(2*m    ) & 7];
            const float4* r2 = (const float4*)rows[(2*m + 1) & 7];
            const float4* r3 = (const float4*)rows[(2*m + 2) & 7];
            float4* xo = (float4*)xv;
            for (int u = tid; u < SEG/4; u += 256) {
                const float4 a = r0[u], b = r1[u], c2 = r2[u], d = r3[u];
                float4 v;
                v.x = fmaf(wy0,a.x, fmaf(wy1,b.x, fmaf(wy2,c2.x, wy3*d.x)));
                v.y = fmaf(wy0,a.y, fmaf(wy1,b.y, fmaf(wy2,c2.y, wy3*d.y)));
                v.z = fmaf(wy0,a.z, fmaf(wy1,b.z, fmaf(wy2,c2.z, wy3*d.z)));
                v.w = fmaf(wy0,a.w, fmaf(wy1,b.w, fmaf(wy2,c2.w, wy3*d.w)));
                xo[u] = v;
            }
        }
        // xv visible to all waves; do NOT drain vmcnt (stage stays in flight)
        asm volatile("s_waitcnt lgkmcnt(0)" ::: "memory");
        __builtin_amdgcn_sched_barrier(0);
        __builtin_amdgcn_s_barrier();

        // l-conv + horizontal 4-tap + H multiply -> global store
        const float* hcur = hb[m & 1];
        float* Xrow = Xm + (size_t)m*LCH*MDIM + n0;
        for (int idx = tid; idx < LCH*TNK; idx += 256) {
            const int l  = idx >> 5;        // 0..30
            const int nl = idx & (TNK-1);
            const int n  = n0 + nl;
            float wx0=0.125f, wx1=0.375f, wx2=0.375f, wx3=0.125f;
            if (n == 0)        wx0 = 0.f;
            if (n == MDIM-1)   wx3 = 0.f;
            if (n == 0 || n == MDIM-1) {
                const float inv = 1.0f/0.875f;
                wx0*=inv; wx1*=inv; wx2*=inv; wx3*=inv;
            }
            const float wb[4] = {wx0, wx1, wx2, wx3};
            // xv[i] <-> q = qa + i; (local col cl, l) at i = cl*31 + l + 1
            const float* p0 = xv + 2*nl*LCH + l + 1;
            float acc = 0.f;
            #pragma unroll
            for (int b = 0; b < 4; ++b) {
                const float* p = p0 + b*LCH;
                float c = 0.5f*p[0];
                if (l > 0)      c += 0.25f*p[-1];
                if (l < LCH-1)  c += 0.25f*p[1];
                acc = fmaf(wb[b], c, acc);
            }
            Xrow[(size_t)l*MDIM + nl] = acc * hcur[nl*LCH + l];
        }
        // staged rows/H for m+1 landed; everyone done with xv
        asm volatile("s_waitcnt vmcnt(0)" ::: "memory");
        __builtin_amdgcn_sched_barrier(0);
        __builtin_amdgcn_s_barrier();
    }
}

// K2: yn[m,c] = sum_i Xm[m][i][c-i]; per-row max -> pmaxY[m] (plain store).
__global__ __launch_bounds__(256) void k2_shiftsum(const float* __restrict__ Xm,
                                                   float* __restrict__ yn,
                                                   float* __restrict__ pmaxY) {
    const int m = blockIdx.x;
    const float* base = Xm + (size_t)m*LCH*MDIM;
    float lmax = -3.4e38f;
    for (int c = threadIdx.x; c < CDIM; c += 256) {
        float s = 0.f;
        const int ilo = max(0, c - (MDIM-1));
        const int ihi = min(LCH-1, c);
        for (int i = ilo; i <= ihi; ++i)
            s += base[(size_t)i*MDIM + (c - i)];
        yn[m*CDIM + c] = s;
        lmax = fmaxf(lmax, s);
    }
    __shared__ float red[256];
    red[threadIdx.x] = lmax; __syncthreads();
    for (int s = 128; s > 0; s >>= 1) {
        if ((int)threadIdx.x < s)
            red[threadIdx.x] = fmaxf(red[threadIdx.x], red[threadIdx.x+s]);
        __syncthreads();
    }
    if (threadIdx.x == 0) pmaxY[m] = red[0];
}

// Reduce n partial maxes -> out_inv[0] = 1/max. Single block, deterministic.
__global__ __launch_bounds__(256) void kmax_reduce(const float* __restrict__ pmax,
                                                   int n,
                                                   float* __restrict__ out_inv) {
    __shared__ float red[256];
    float lmax = -3.4e38f;
    for (int i = threadIdx.x; i < n; i += 256)
        lmax = fmaxf(lmax, pmax[i]);
    red[threadIdx.x] = lmax; __syncthreads();
    for (int s = 128; s > 0; s >>= 1) {
        if ((int)threadIdx.x < s)
            red[threadIdx.x] = fmaxf(red[threadIdx.x], red[threadIdx.x+s]);
        __syncthreads();
    }
    if (threadIdx.x == 0) out_inv[0] = 1.0f / red[0];
}

// t(idx) = H[idx] * conv_i(yn/My - y at c=n+i)  -- shared by k3 (max) and k4 (write)
__device__ __forceinline__ float t_elem(int idx,
                                        const float* __restrict__ yn,
                                        const float* __restrict__ y,
                                        const float* __restrict__ H,
                                        float inv) {
    const int i    = idx % LCH;
    const int rest = idx / LCH;
    const int n    = rest & (MDIM-1);
    const int m    = rest >> 9;
    const int c    = n + i;
    const float* ynr = yn + (size_t)m*CDIM;
    const float* yr  = y  + (size_t)m*CDIM;
    float v = 0.5f * (ynr[c]*inv - yr[c]);
    if (i > 0)     v += 0.25f*(ynr[c-1]*inv - yr[c-1]);
    if (i < LCH-1) v += 0.25f*(ynr[c+1]*inv - yr[c+1]);
    return H[idx]*v;
}

// K3: block-max of t over grid-stride range -> pmaxT[bid]. No stores of t.
__global__ __launch_bounds__(256) void k3_max(const float* __restrict__ yn,
                                              const float* __restrict__ y,
                                              const float* __restrict__ H,
                                              const float* __restrict__ scl,
                                              float* __restrict__ pmaxT) {
    const float inv = scl[0];
    float lmax = -3.4e38f;
    for (int idx = blockIdx.x*blockDim.x + threadIdx.x; idx < NELEM;
         idx += GB3*256)
        lmax = fmaxf(lmax, t_elem(idx, yn, y, H, inv));
    __shared__ float red[256];
    red[threadIdx.x] = lmax; __syncthreads();
    for (int s = 128; s > 0; s >>= 1) {
        if ((int)threadIdx.x < s)
            red[threadIdx.x] = fmaxf(red[threadIdx.x], red[threadIdx.x+s]);
        __syncthreads();
    }
    if (threadIdx.x == 0) pmaxT[blockIdx.x] = red[0];
}

// K4: recompute t, scale by 1/maxT, write out (coalesced, single pass).
__global__ __launch_bounds__(256) void k4_out(const float* __restrict__ yn,
                                              const float* __restrict__ y,
                                              const float* __restrict__ H,
                                              const float* __restrict__ scl,
                                              float* __restrict__ out) {
    const float inv  = scl[0];
    const float invT = scl[1];
    for (int idx = blockIdx.x*blockDim.x + threadIdx.x; idx < NELEM;
         idx += GB3*256)
        out[idx] = t_elem(idx, yn, y, H, inv) * invT;
}

extern "C" void kernel_launch(void* const* d_in, const int* in_sizes, int n_in,
                              void* d_out, int out_size, void* d_ws, size_t ws_size,
                              hipStream_t stream) {
    const float* X = (const float*)d_in[0];
    const float* y = (const float*)d_in[1];
    const float* H = (const float*)d_in[2];
    float* out = (float*)d_out;
    float* ws  = (float*)d_ws;

    float* Xm    = ws + XM_OFF;
    float* yn    = ws + YN_OFF;
    float* pmaxY = ws + PMY_OFF;
    float* pmaxT = ws + PMT_OFF;
    float* scl   = ws + SCL_OFF;   // [0]=1/maxY, [1]=1/maxT

    k1_fused<<<(MDIM/MPER)*16, 256, 0, stream>>>(X, H, Xm);         // 512 blocks
    k2_shiftsum<<<MDIM, 256, 0, stream>>>(Xm, yn, pmaxY);           // 512 blocks
    kmax_reduce<<<1, 256, 0, stream>>>(pmaxY, MDIM, scl);
    k3_max<<<GB3, 256, 0, stream>>>(yn, y, H, scl, pmaxT);          // 2048 blocks
    kmax_reduce<<<1, 256, 0, stream>>>(pmaxT, GB3, scl + 1);
    k4_out<<<GB3, 256, 0, stream>>>(yn, y, H, scl, out);
}

// Round 8
// 110.229 us; speedup vs baseline: 1.1487x; 1.1487x over previous
//
#include <hip/hip_runtime.h>

#define MDIM 512
#define LCH  31
#define CDIM 542   // MD + L - 1
#define INW  1024
#define TN   64                 // output n-columns per block (k1)
#define NELEM (MDIM*MDIM*LCH)   // 8126464
#define GB3  2048               // k3/k4 grid blocks

// ws layout (floats): Xm[m][l][n], yn[m][c], pmaxY[512], pmaxT[2048], scl[2]
#define XM_OFF  0
#define YN_OFF  (MDIM*LCH*MDIM)
#define PMY_OFF (YN_OFF + MDIM*CDIM)
#define PMT_OFF (PMY_OFF + MDIM)
#define SCL_OFF (PMT_OFF + GB3)

// K1: fused bilinear-resize + l-conv + H-mult.
// Block = (m, n-tile of 64). Phase 1 issues all 16 global_load_dwordx4
// back-to-back per thread. __launch_bounds__(256, 2) is the load-bearing
// part: it raises the VGPR cap to 128 so the compiler can keep all 16
// float4 temporaries live (r6 identical structure at default bounds got
// VGPR=32 -> loads re-serialized -> latency-bound at 75us).
// Clamped addresses: every OOB tile entry is consumed only with a zero
// horizontal weight (col -1 <-> wx0=0 at n=0; col 1024 <-> wx3=0 at n=511).
__global__ __launch_bounds__(256, 2) void k1_fused(const float* __restrict__ X,
                                                   const float* __restrict__ H,
                                                   float* __restrict__ Xm) {
    __shared__ float xv[4096];          // 16 KB; tile uses [0,4032), rest pad

    const int m     = blockIdx.x >> 3;  // bid = m*8 + ntile
    const int ntile = blockIdx.x & 7;
    const int n0    = ntile * TN;
    const int t     = threadIdx.x;

    float wy0=0.125f, wy1=0.375f, wy2=0.375f, wy3=0.125f;
    if (m == 0)        wy0 = 0.f;
    if (m == MDIM-1)   wy3 = 0.f;
    if (m == 0 || m == MDIM-1) {
        const float inv = 1.0f/0.875f;
        wy0*=inv; wy1*=inv; wy2*=inv; wy3*=inv;
    }
    const int rr0 = 2*m - 1;
    const int RS  = INW*LCH;            // floats per input row = 31744
    const float* xr0 = X + (size_t)min(max(rr0+0,0),INW-1)*RS;
    const float* xr1 = X + (size_t)(rr0+1)*RS;
    const float* xr2 = X + (size_t)(rr0+2)*RS;
    const float* xr3 = X + (size_t)min(max(rr0+3,0),INW-1)*RS;

    const int qa = (2*n0 - 1)*LCH - 1;  // float4-aligned tile start (q offset)

    // phase 1: vertical 4-tap resize. All 16 loads issued before any use.
    int qs[4];
    #pragma unroll
    for (int j = 0; j < 4; ++j) {
        int q0 = qa + 4*(t + 256*j);
        qs[j] = min(max(q0, 0), RS - 4);   // clamp; OOB lanes feed zero-weight taps
    }
    float4 A[4], B[4], C[4], D[4];
    #pragma unroll
    for (int j = 0; j < 4; ++j) A[j] = *(const float4*)(xr0 + qs[j]);
    #pragma unroll
    for (int j = 0; j < 4; ++j) B[j] = *(const float4*)(xr1 + qs[j]);
    #pragma unroll
    for (int j = 0; j < 4; ++j) C[j] = *(const float4*)(xr2 + qs[j]);
    #pragma unroll
    for (int j = 0; j < 4; ++j) D[j] = *(const float4*)(xr3 + qs[j]);
    #pragma unroll
    for (int j = 0; j < 4; ++j) {
        float4 a;
        a.x = fmaf(wy0,A[j].x, fmaf(wy1,B[j].x, fmaf(wy2,C[j].x, wy3*D[j].x)));
        a.y = fmaf(wy0,A[j].y, fmaf(wy1,B[j].y, fmaf(wy2,C[j].y, wy3*D[j].y)));
        a.z = fmaf(wy0,A[j].z, fmaf(wy1,B[j].z, fmaf(wy2,C[j].z, wy3*D[j].z)));
        a.w = fmaf(wy0,A[j].w, fmaf(wy1,B[j].w, fmaf(wy2,C[j].w, wy3*D[j].w)));
        *(float4*)&xv[4*(t + 256*j)] = a;
    }
    __syncthreads();

    // phase 2: l-conv (in-LDS taps) + horizontal 4-tap + H multiply
    const float* Hrow = H + ((size_t)m*MDIM + n0)*LCH;
    float* Xrow = Xm + (size_t)m*LCH*MDIM + n0;
    for (int idx = t; idx < LCH*TN; idx += 256) {
        const int l  = idx >> 6;        // 0..30
        const int nl = idx & (TN-1);
        const int n  = n0 + nl;
        float wx0=0.125f, wx1=0.375f, wx2=0.375f, wx3=0.125f;
        if (n == 0)        wx0 = 0.f;
        if (n == MDIM-1)   wx3 = 0.f;
        if (n == 0 || n == MDIM-1) {
            const float inv = 1.0f/0.875f;
            wx0*=inv; wx1*=inv; wx2*=inv; wx3*=inv;
        }
        const float wb[4] = {wx0, wx1, wx2, wx3};
        // xv[i] holds q = qa + i; tap (col=2n-1+b, l) at i = 2nl*31 + l + 1 + 31b
        const float* p0 = xv + 2*nl*LCH + l + 1;
        float acc = 0.f;
        #pragma unroll
        for (int b = 0; b < 4; ++b) {
            const float* p = p0 + b*LCH;
            float c = 0.5f*p[0];
            if (l > 0)      c += 0.25f*p[-1];
            if (l < LCH-1)  c += 0.25f*p[1];
            acc = fmaf(wb[b], c, acc);
        }
        Xrow[(size_t)l*MDIM + nl] = acc * Hrow[nl*LCH + l];
    }
}

// K2: yn[m,c] = sum_i Xm[m][i][c-i]; per-row max -> pmaxY[m] (plain store).
__global__ __launch_bounds__(256) void k2_shiftsum(const float* __restrict__ Xm,
                                                   float* __restrict__ yn,
                                                   float* __restrict__ pmaxY) {
    const int m = blockIdx.x;
    const float* base = Xm + (size_t)m*LCH*MDIM;
    float lmax = -3.4e38f;
    for (int c = threadIdx.x; c < CDIM; c += 256) {
        float s = 0.f;
        const int ilo = max(0, c - (MDIM-1));
        const int ihi = min(LCH-1, c);
        for (int i = ilo; i <= ihi; ++i)
            s += base[(size_t)i*MDIM + (c - i)];
        yn[m*CDIM + c] = s;
        lmax = fmaxf(lmax, s);
    }
    __shared__ float red[256];
    red[threadIdx.x] = lmax; __syncthreads();
    for (int s = 128; s > 0; s >>= 1) {
        if ((int)threadIdx.x < s)
            red[threadIdx.x] = fmaxf(red[threadIdx.x], red[threadIdx.x+s]);
        __syncthreads();
    }
    if (threadIdx.x == 0) pmaxY[m] = red[0];
}

// Reduce n partial maxes -> out_inv[0] = 1/max. Single block, deterministic.
__global__ __launch_bounds__(256) void kmax_reduce(const float* __restrict__ pmax,
                                                   int n,
                                                   float* __restrict__ out_inv) {
    __shared__ float red[256];
    float lmax = -3.4e38f;
    for (int i = threadIdx.x; i < n; i += 256)
        lmax = fmaxf(lmax, pmax[i]);
    red[threadIdx.x] = lmax; __syncthreads();
    for (int s = 128; s > 0; s >>= 1) {
        if ((int)threadIdx.x < s)
            red[threadIdx.x] = fmaxf(red[threadIdx.x], red[threadIdx.x+s]);
        __syncthreads();
    }
    if (threadIdx.x == 0) out_inv[0] = 1.0f / red[0];
}

// t(idx) = H[idx] * conv_i(yn/My - y at c=n+i)  -- shared by k3 (max) and k4 (write)
__device__ __forceinline__ float t_elem(int idx,
                                        const float* __restrict__ yn,
                                        const float* __restrict__ y,
                                        const float* __restrict__ H,
                                        float inv) {
    const int i    = idx % LCH;
    const int rest = idx / LCH;
    const int n    = rest & (MDIM-1);
    const int m    = rest >> 9;
    const int c    = n + i;
    const float* ynr = yn + (size_t)m*CDIM;
    const float* yr  = y  + (size_t)m*CDIM;
    float v = 0.5f * (ynr[c]*inv - yr[c]);
    if (i > 0)     v += 0.25f*(ynr[c-1]*inv - yr[c-1]);
    if (i < LCH-1) v += 0.25f*(ynr[c+1]*inv - yr[c+1]);
    return H[idx]*v;
}

// K3: block-max of t over grid-stride range -> pmaxT[bid]. No stores of t.
__global__ __launch_bounds__(256) void k3_max(const float* __restrict__ yn,
                                              const float* __restrict__ y,
                                              const float* __restrict__ H,
                                              const float* __restrict__ scl,
                                              float* __restrict__ pmaxT) {
    const float inv = scl[0];
    float lmax = -3.4e38f;
    for (int idx = blockIdx.x*blockDim.x + threadIdx.x; idx < NELEM;
         idx += GB3*256)
        lmax = fmaxf(lmax, t_elem(idx, yn, y, H, inv));
    __shared__ float red[256];
    red[threadIdx.x] = lmax; __syncthreads();
    for (int s = 128; s > 0; s >>= 1) {
        if ((int)threadIdx.x < s)
            red[threadIdx.x] = fmaxf(red[threadIdx.x], red[threadIdx.x+s]);
        __syncthreads();
    }
    if (threadIdx.x == 0) pmaxT[blockIdx.x] = red[0];
}

// K4: recompute t, scale by 1/maxT, write out (coalesced, single pass).
__global__ __launch_bounds__(256) void k4_out(const float* __restrict__ yn,
                                              const float* __restrict__ y,
                                              const float* __restrict__ H,
                                              const float* __restrict__ scl,
                                              float* __restrict__ out) {
    const float inv  = scl[0];
    const float invT = scl[1];
    for (int idx = blockIdx.x*blockDim.x + threadIdx.x; idx < NELEM;
         idx += GB3*256)
        out[idx] = t_elem(idx, yn, y, H, inv) * invT;
}

extern "C" void kernel_launch(void* const* d_in, const int* in_sizes, int n_in,
                              void* d_out, int out_size, void* d_ws, size_t ws_size,
                              hipStream_t stream) {
    const float* X = (const float*)d_in[0];
    const float* y = (const float*)d_in[1];
    const float* H = (const float*)d_in[2];
    float* out = (float*)d_out;
    float* ws  = (float*)d_ws;

    float* Xm    = ws + XM_OFF;
    float* yn    = ws + YN_OFF;
    float* pmaxY = ws + PMY_OFF;
    float* pmaxT = ws + PMT_OFF;
    float* scl   = ws + SCL_OFF;   // [0]=1/maxY, [1]=1/maxT

    k1_fused<<<MDIM*8, 256, 0, stream>>>(X, H, Xm);                 // 4096 blocks
    k2_shiftsum<<<MDIM, 256, 0, stream>>>(Xm, yn, pmaxY);           // 512 blocks
    kmax_reduce<<<1, 256, 0, stream>>>(pmaxY, MDIM, scl);
    k3_max<<<GB3, 256, 0, stream>>>(yn, y, H, scl, pmaxT);          // 2048 blocks
    kmax_reduce<<<1, 256, 0, stream>>>(pmaxT, GB3, scl + 1);
    k4_out<<<GB3, 256, 0, stream>>>(yn, y, H, scl, out);
}

// Round 9
// 90.787 us; speedup vs baseline: 1.3947x; 1.2142x over previous
//
#include <hip/hip_runtime.h>

#define MDIM 512
#define LCH  31
#define CDIM 542   // MD + L - 1
#define INW  1024
#define RS   (INW*LCH)          // floats per input row = 31744
#define NELEM (MDIM*MDIM*LCH)   // 8126464
#define GB3  2048               // k3/k4 grid blocks

#define TNK  32                 // output n-cols per k1 tile
#define NT   16                 // tiles per row (512/32)
#define NPAIR 256               // m-pairs

// ws layout (floats): part[pair][tile][mm][128], yn[m][c], pmaxY, pmaxT, scl
#define PART_OFF 0
#define PART_SZ  (NPAIR*NT*2*128)        // 1048576
#define YN_OFF   (PART_OFF + PART_SZ)
#define PMY_OFF  (YN_OFF + MDIM*CDIM)
#define PMT_OFF  (PMY_OFF + MDIM)
#define SCL_OFF  (PMT_OFF + GB3)

// K1: fused bilinear-resize + l-conv + H-mult + CASSI diagonal partial sums.
// Block = (m-pair p, n-tile of 32). 6 input rows serve BOTH output rows
// (vertical combine in registers during load -> X touched 1.5x instead of 2x).
// No Xm intermediate: the xm tile is reduced along diagonals (c = n + l) to
// per-block partials in ws; k2_lite assembles yn. All clamped/garbage LDS
// entries are consumed only with zero weights:
//   col -1 / 1024 -> wx0/wx3 = 0 at n = 0/511 (incl. their l+-1 conv taps)
//   row -1 / 1024 -> wa0/wb3 = 0 at m = 0/511
__global__ __launch_bounds__(256) void k1_fused(const float* __restrict__ X,
                                                const float* __restrict__ H,
                                                float* __restrict__ part) {
    __shared__ float xv[2][2048];     // vertically-resized flat tiles (16.4 KB)
    __shared__ float xm[2][32][33];   // H*conv tile, padded stride 33 (8.4 KB)

    const int bid = blockIdx.x;
    const int t   = bid & (NT-1);
    const int p   = bid >> 4;
    const int n0  = t * TNK;
    const int m0  = 2*p;
    const int tid = threadIdx.x;
    const int qa  = 1984*t - 32;      // float4-aligned staged-q origin

    // ---- phase 1: load 6 rows x 2 positions, vertical 4-tap for both m ----
    const float* rp0 = X + (size_t)max(4*p - 1, 0) * RS;
    const float* rp1 = X + (size_t)(4*p    ) * RS;
    const float* rp2 = X + (size_t)(4*p + 1) * RS;
    const float* rp3 = X + (size_t)(4*p + 2) * RS;
    const float* rp4 = X + (size_t)(4*p + 3) * RS;
    const float* rp5 = X + (size_t)min(4*p + 4, INW-1) * RS;

    float wa0=0.125f, wa1=0.375f, wa2=0.375f, wa3=0.125f;   // m = m0   (rows 0..3)
    if (m0 == 0) {
        const float s = 1.0f/0.875f;
        wa0 = 0.f; wa1 = 0.375f*s; wa2 = 0.375f*s; wa3 = 0.125f*s;
    }
    float wb0=0.125f, wb1=0.375f, wb2=0.375f, wb3=0.125f;   // m = m0+1 (rows 2..5)
    if (m0 + 1 == MDIM-1) {
        const float s = 1.0f/0.875f;
        wb0 = 0.125f*s; wb1 = 0.375f*s; wb2 = 0.375f*s; wb3 = 0.f;
    }

    #pragma unroll
    for (int j = 0; j < 2; ++j) {
        const int u = tid + 256*j;
        int q = qa + 4*u;
        q = min(max(q, 0), RS - 4);   // clamp -> zero-weight taps only
        const float4 r0 = *(const float4*)(rp0 + q);
        const float4 r1 = *(const float4*)(rp1 + q);
        const float4 r2 = *(const float4*)(rp2 + q);
        const float4 r3 = *(const float4*)(rp3 + q);
        const float4 r4 = *(const float4*)(rp4 + q);
        const float4 r5 = *(const float4*)(rp5 + q);
        float4 va, vb;
        va.x = fmaf(wa0,r0.x, fmaf(wa1,r1.x, fmaf(wa2,r2.x, wa3*r3.x)));
        va.y = fmaf(wa0,r0.y, fmaf(wa1,r1.y, fmaf(wa2,r2.y, wa3*r3.y)));
        va.z = fmaf(wa0,r0.z, fmaf(wa1,r1.z, fmaf(wa2,r2.z, wa3*r3.z)));
        va.w = fmaf(wa0,r0.w, fmaf(wa1,r1.w, fmaf(wa2,r2.w, wa3*r3.w)));
        vb.x = fmaf(wb0,r2.x, fmaf(wb1,r3.x, fmaf(wb2,r4.x, wb3*r5.x)));
        vb.y = fmaf(wb0,r2.y, fmaf(wb1,r3.y, fmaf(wb2,r4.y, wb3*r5.y)));
        vb.z = fmaf(wb0,r2.z, fmaf(wb1,r3.z, fmaf(wb2,r4.z, wb3*r5.z)));
        vb.w = fmaf(wb0,r2.w, fmaf(wb1,r3.w, fmaf(wb2,r4.w, wb3*r5.w)));
        *(float4*)&xv[0][4*u] = va;
        *(float4*)&xv[1][4*u] = vb;
    }
    __syncthreads();

    // ---- phase 2: l-conv + horizontal 4-tap + H multiply -> xm tile ----
    // xv[mm][i] holds vert(q = qa + i); tap (col = 2n-1+b, l) at
    // i = 2*nl*31 + 31*b + l + 1.
    const size_t hbase = ((size_t)m0*MDIM + n0)*LCH;
    for (int idx = tid; idx < 2*TNK*LCH; idx += 256) {   // 1984
        const int mm = idx >= TNK*LCH;
        const int r2 = mm ? idx - TNK*LCH : idx;
        const int nl = r2 / 31;
        const int l  = r2 - nl*31;
        const int n  = n0 + nl;
        float wx0=0.125f, wx1=0.375f, wx2=0.375f, wx3=0.125f;
        if (n == 0)      wx0 = 0.f;
        if (n == MDIM-1) wx3 = 0.f;
        if (n == 0 || n == MDIM-1) {
            const float s = 1.0f/0.875f;
            wx0*=s; wx1*=s; wx2*=s; wx3*=s;
        }
        const float wb4[4] = {wx0, wx1, wx2, wx3};
        const float* xvm = xv[mm];
        const int ib = 2*nl*31 + l + 1;
        float acc = 0.f;
        #pragma unroll
        for (int b = 0; b < 4; ++b) {
            const float* q = xvm + ib + 31*b;
            float c = 0.5f*q[0];
            if (l > 0)  c += 0.25f*q[-1];
            if (l < 30) c += 0.25f*q[1];
            acc = fmaf(wb4[b], c, acc);
        }
        const float hv = H[hbase + (size_t)mm*(MDIM*LCH) + r2];  // contiguous
        xm[mm][nl][l] = acc * hv;
    }
    __syncthreads();

    // ---- phase 3: diagonal partial sums: c = n + l, cl = c - n0 in [0,62) ----
    if (tid < 248) {
        const int mm = tid >= 124;
        const int r3 = mm ? tid - 124 : tid;
        const int h  = r3 >= 62;
        const int cl = h ? r3 - 62 : r3;
        const int ilo = max(0, cl - (TNK-1));
        const int ihi = min(30, cl);
        const int mid = (ilo + ihi + 1) >> 1;
        const int lo  = h ? mid : ilo;
        const int hi  = h ? ihi : mid - 1;
        float s = 0.f;
        for (int i = lo; i <= hi; ++i)
            s += xm[mm][cl - i][i];          // stride-33 -> conflict-free
        part[(((size_t)p*NT + t)*2 + mm)*128 + h*64 + cl] = s;
    }
}

// K2_lite: yn[m][c] = sum of <=2 tile-partials x 2 halves; per-row max.
__global__ __launch_bounds__(256) void k2_lite(const float* __restrict__ part,
                                               float* __restrict__ yn,
                                               float* __restrict__ pmaxY) {
    const int m = blockIdx.x;
    const int p = m >> 1, mm = m & 1;
    float lmax = -3.4e38f;
    for (int c = threadIdx.x; c < CDIM; c += 256) {
        float s = 0.f;
        const int tlo = max(0, (c - 30) >> 5);      // ceil((c-61)/32) for c>=61
        const int thi = min(NT - 1, c >> 5);
        for (int t = tlo; t <= thi; ++t) {
            const int cl = c - TNK*t;               // in [0,62)
            const float* pp = part + (((size_t)p*NT + t)*2 + mm)*128;
            s += pp[cl] + pp[64 + cl];
        }
        yn[m*CDIM + c] = s;
        lmax = fmaxf(lmax, s);
    }
    __shared__ float red[256];
    red[threadIdx.x] = lmax; __syncthreads();
    for (int s = 128; s > 0; s >>= 1) {
        if ((int)threadIdx.x < s)
            red[threadIdx.x] = fmaxf(red[threadIdx.x], red[threadIdx.x+s]);
        __syncthreads();
    }
    if (threadIdx.x == 0) pmaxY[m] = red[0];
}

// Reduce n partial maxes -> out_inv[0] = 1/max. Single block, deterministic.
__global__ __launch_bounds__(256) void kmax_reduce(const float* __restrict__ pmax,
                                                   int n,
                                                   float* __restrict__ out_inv) {
    __shared__ float red[256];
    float lmax = -3.4e38f;
    for (int i = threadIdx.x; i < n; i += 256)
        lmax = fmaxf(lmax, pmax[i]);
    red[threadIdx.x] = lmax; __syncthreads();
    for (int s = 128; s > 0; s >>= 1) {
        if ((int)threadIdx.x < s)
            red[threadIdx.x] = fmaxf(red[threadIdx.x], red[threadIdx.x+s]);
        __syncthreads();
    }
    if (threadIdx.x == 0) out_inv[0] = 1.0f / red[0];
}

// t(idx) = H[idx] * conv_i(yn/My - y at c=n+i)  -- shared by k3 (max) and k4
__device__ __forceinline__ float t_elem(int idx,
                                        const float* __restrict__ yn,
                                        const float* __restrict__ y,
                                        const float* __restrict__ H,
                                        float inv) {
    const int i    = idx % LCH;
    const int rest = idx / LCH;
    const int n    = rest & (MDIM-1);
    const int m    = rest >> 9;
    const int c    = n + i;
    const float* ynr = yn + (size_t)m*CDIM;
    const float* yr  = y  + (size_t)m*CDIM;
    float v = 0.5f * (ynr[c]*inv - yr[c]);
    if (i > 0)     v += 0.25f*(ynr[c-1]*inv - yr[c-1]);
    if (i < LCH-1) v += 0.25f*(ynr[c+1]*inv - yr[c+1]);
    return H[idx]*v;
}

// K3: block-max of t over grid-stride range -> pmaxT[bid]. No stores of t.
__global__ __launch_bounds__(256) void k3_max(const float* __restrict__ yn,
                                              const float* __restrict__ y,
                                              const float* __restrict__ H,
                                              const float* __restrict__ scl,
                                              float* __restrict__ pmaxT) {
    const float inv = scl[0];
    float lmax = -3.4e38f;
    for (int idx = blockIdx.x*blockDim.x + threadIdx.x; idx < NELEM;
         idx += GB3*256)
        lmax = fmaxf(lmax, t_elem(idx, yn, y, H, inv));
    __shared__ float red[256];
    red[threadIdx.x] = lmax; __syncthreads();
    for (int s = 128; s > 0; s >>= 1) {
        if ((int)threadIdx.x < s)
            red[threadIdx.x] = fmaxf(red[threadIdx.x], red[threadIdx.x+s]);
        __syncthreads();
    }
    if (threadIdx.x == 0) pmaxT[blockIdx.x] = red[0];
}

// K4: recompute t, scale by 1/maxT, write out (coalesced, single pass).
__global__ __launch_bounds__(256) void k4_out(const float* __restrict__ yn,
                                              const float* __restrict__ y,
                                              const float* __restrict__ H,
                                              const float* __restrict__ scl,
                                              float* __restrict__ out) {
    const float inv  = scl[0];
    const float invT = scl[1];
    for (int idx = blockIdx.x*blockDim.x + threadIdx.x; idx < NELEM;
         idx += GB3*256)
        out[idx] = t_elem(idx, yn, y, H, inv) * invT;
}

extern "C" void kernel_launch(void* const* d_in, const int* in_sizes, int n_in,
                              void* d_out, int out_size, void* d_ws, size_t ws_size,
                              hipStream_t stream) {
    const float* X = (const float*)d_in[0];
    const float* y = (const float*)d_in[1];
    const float* H = (const float*)d_in[2];
    float* out = (float*)d_out;
    float* ws  = (float*)d_ws;

    float* part  = ws + PART_OFF;
    float* yn    = ws + YN_OFF;
    float* pmaxY = ws + PMY_OFF;
    float* pmaxT = ws + PMT_OFF;
    float* scl   = ws + SCL_OFF;   // [0]=1/maxY, [1]=1/maxT

    k1_fused<<<NPAIR*NT, 256, 0, stream>>>(X, H, part);   // 4096 blocks
    k2_lite<<<MDIM, 256, 0, stream>>>(part, yn, pmaxY);   // 512 blocks
    kmax_reduce<<<1, 256, 0, stream>>>(pmaxY, MDIM, scl);
    k3_max<<<GB3, 256, 0, stream>>>(yn, y, H, scl, pmaxT);
    kmax_reduce<<<1, 256, 0, stream>>>(pmaxT, GB3, scl + 1);
    k4_out<<<GB3, 256, 0, stream>>>(yn, y, H, scl, out);
}